// Round 4
// baseline (201.065 us; speedup 1.0000x reference)
//
#include <hip/hip_runtime.h>
#include <hip/hip_bf16.h>
#include <math.h>

typedef __bf16 bf16_t;
typedef __bf16 bf16x4 __attribute__((ext_vector_type(4)));
typedef __bf16 bf16x8 __attribute__((ext_vector_type(8)));
typedef float  f32x4  __attribute__((ext_vector_type(4)));

#define LOG2E   1.4426950408889634f
#define QSCALE  0.04419417382415922f            /* 1/sqrt(512) */
#define QS_TOT  (QSCALE * LOG2E)                /* folded into Wq/bq: scores in log2 units */
#define DEFER_THR 8.0f

static __device__ __forceinline__ f32x4 mfma16(bf16x8 a, bf16x8 b, f32x4 c) {
    return __builtin_amdgcn_mfma_f32_16x16x32_bf16(a, b, c, 0, 0, 0);
}

static __device__ __forceinline__ void gload16(void* lds, const void* g) {
    __builtin_amdgcn_global_load_lds(
        (const __attribute__((address_space(1))) unsigned int*)g,
        (__attribute__((address_space(3))) unsigned int*)lds, 16, 0, 0);
}

// ---------------- staging ----------------

__global__ void k_stage_x(const float* __restrict__ x, bf16_t* __restrict__ xb) {
    int i = (blockIdx.x * blockDim.x + threadIdx.x) * 4;
    f32x4 v = *(const f32x4*)(x + i);
    bf16x4 o;
    o[0] = (bf16_t)v[0]; o[1] = (bf16_t)v[1]; o[2] = (bf16_t)v[2]; o[3] = (bf16_t)v[3];
    *(bf16x4*)(xb + i) = o;
}

// LDS-tiled transpose: W*[h][d][c] (f32) -> Wcat[h*320 + part_off + c][d] (bf16)
__global__ void k_stage_wt(const float* __restrict__ Wq, const float* __restrict__ Wk,
                           const float* __restrict__ Wv, bf16_t* __restrict__ Wcat) {
    __shared__ float tl[64][65];
    int p = blockIdx.y;
    int bid = blockIdx.x;                    // 128
    int h = bid >> 4, rem = bid & 15, dt = rem >> 1, ct = rem & 1;
    if (p == 2 && ct) return;
    int cols = (p == 2) ? 64 : 128;
    const float* src = (p == 0 ? Wq : (p == 1 ? Wk : Wv)) + h * 512 * cols;
    int d0 = dt * 64, c0 = ct * 64;
    int cin = threadIdx.x & 63, rb = threadIdx.x >> 6;
    #pragma unroll
    for (int j = 0; j < 16; j++) {
        int dl = rb * 16 + j;
        tl[dl][cin] = src[(d0 + dl) * cols + c0 + cin];
    }
    __syncthreads();
    float sc = (p == 0) ? QS_TOT : 1.0f;
    int nl = threadIdx.x >> 2, dch = (threadIdx.x & 3) * 16;
    int n = h * 320 + p * 128 + c0 + nl;
    bf16_t* dst = Wcat + n * 512 + d0 + dch;
    #pragma unroll
    for (int e = 0; e < 16; e += 4) {
        bf16x4 o;
        #pragma unroll
        for (int q = 0; q < 4; q++) o[q] = (bf16_t)(tl[dch + e + q][nl] * sc);
        *(bf16x4*)(dst + e) = o;
    }
}

__global__ void k_stage_bias(const float* __restrict__ bq, const float* __restrict__ bk,
                             const float* __restrict__ bv, float* __restrict__ bcat) {
    int n = blockIdx.x * blockDim.x + threadIdx.x;
    if (n >= 2560) return;
    int h = n / 320, r = n % 320;
    float v;
    if (r < 128)      v = bq[h * 128 + r] * QS_TOT;
    else if (r < 256) v = bk[h * 128 + r - 128];
    else              v = bv[h * 64 + r - 256];
    bcat[n] = v;
}

// Wo[hv=512][dout=512] f32 -> Wot[dout][hv] bf16, LDS-tiled
__global__ void k_stage_wo_t(const float* __restrict__ Wo, bf16_t* __restrict__ Wot) {
    __shared__ float tl[64][65];
    int r0 = blockIdx.x * 64, c0 = blockIdx.y * 64;
    int cin = threadIdx.x & 63, rb = threadIdx.x >> 6;
    #pragma unroll
    for (int j = 0; j < 16; j++) {
        int rl = rb * 16 + j;
        tl[rl][cin] = Wo[(r0 + rl) * 512 + c0 + cin];
    }
    __syncthreads();
    int nl = threadIdx.x >> 2, dch = (threadIdx.x & 3) * 16;
    bf16_t* dst = Wot + (c0 + nl) * 512 + r0 + dch;
    #pragma unroll
    for (int e = 0; e < 16; e += 4) {
        bf16x4 o;
        #pragma unroll
        for (int q = 0; q < 4; q++) o[q] = (bf16_t)tl[dch + e + q][nl];
        *(bf16x4*)(dst + e) = o;
    }
}

// ---------------- QKV projection GEMM ----------------
__global__ __launch_bounds__(256) void k_gemm_qkv(
        const bf16_t* __restrict__ xb, const bf16_t* __restrict__ Wcat,
        const float* __restrict__ bcat,
        bf16_t* __restrict__ Qb, bf16_t* __restrict__ Kb, bf16_t* __restrict__ Vt) {
    int lane = threadIdx.x & 63, wv = threadIdx.x >> 6;
    int rbase = blockIdx.x * 128 + wv * 32;
    int cbase = blockIdx.y * 64;
    int row = lane & 15, g = lane >> 4;

    const bf16_t* ap = xb + (rbase + row) * 512 + g * 8;
    const bf16_t* bp = Wcat + (cbase + row) * 512 + g * 8;
    f32x4 acc[2][4];
    #pragma unroll
    for (int at = 0; at < 2; at++)
        #pragma unroll
        for (int cc = 0; cc < 4; cc++) acc[at][cc] = (f32x4){0.f,0.f,0.f,0.f};
    #pragma unroll 4
    for (int kk = 0; kk < 512; kk += 32) {
        bf16x8 a0 = *(const bf16x8*)(ap + kk);
        bf16x8 a1 = *(const bf16x8*)(ap + 16 * 512 + kk);
        #pragma unroll
        for (int cc = 0; cc < 4; cc++) {
            bf16x8 b = *(const bf16x8*)(bp + cc * 16 * 512 + kk);
            acc[0][cc] = mfma16(a0, b, acc[0][cc]);
            acc[1][cc] = mfma16(a1, b, acc[1][cc]);
        }
    }

    #pragma unroll
    for (int cc = 0; cc < 4; cc++) {
        int n = cbase + cc * 16 + row;
        float bias = bcat[n];
        int h = n / 320, r = n % 320;
        #pragma unroll
        for (int at = 0; at < 2; at++)
            #pragma unroll
            for (int i = 0; i < 4; i++) {
                int rr = rbase + at * 16 + g * 4 + i;
                float val = acc[at][cc][i] + bias;
                if (r < 128)      Qb[(h * 4096 + rr) * 128 + r]         = (bf16_t)val;
                else if (r < 256) Kb[(h * 4096 + rr) * 128 + (r - 128)] = (bf16_t)val;
                else {
                    // permuted time slot: key=16b+4gk+ik (within 32) -> 8gk+4b+ik
                    int cp = (rr & ~31) | (((rr >> 2) & 3) << 3) | (((rr >> 4) & 1) << 2) | (rr & 3);
                    Vt[(h * 64 + (r - 256)) * 4096 + cp] = (bf16_t)val;
                }
            }
    }
}

// ---------------- flash attention ----------------
static __device__ __forceinline__ void stage_k(bf16_t* kbuf, const bf16_t* Kh,
                                               int kt, int wv, int lane) {
    #pragma unroll
    for (int j = 0; j < 4; ++j) {
        int local = wv * 16 + j * 4 + (lane >> 4);
        int physcol = (lane & 15) << 4;
        const char* src = (const char*)(Kh + (size_t)(kt + local) * 128)
                        + (physcol ^ ((local & 7) << 4));
        gload16(kbuf + (wv * 16 + j * 4) * 128, src);
    }
}

static __device__ __forceinline__ float vmax4(f32x4 v) {
    return fmaxf(fmaxf(v[0], v[1]), fmaxf(v[2], v[3]));
}

__global__ __launch_bounds__(256, 4) void k_attn(
        const bf16_t* __restrict__ Qb, const bf16_t* __restrict__ Kb,
        const bf16_t* __restrict__ Vt, bf16_t* __restrict__ Cb,
        float* __restrict__ Opart, float* __restrict__ MLpart, int nkeys) {
    __shared__ __align__(16) bf16_t k_lds[2][64 * 128];

    const int lane = threadIdx.x & 63, wv = threadIdx.x >> 6;
    const int qi = lane & 15, g = lane >> 4;

    // bijective XCD-chunked swizzle (nwg = 256*splits, %8==0)
    int nwg = 32 * 8 * gridDim.z, cpx = nwg >> 3;
    int wgid = blockIdx.x + 32 * (blockIdx.y + 8 * blockIdx.z);
    int wk = (wgid & 7) * cpx + (wgid >> 3);
    const int qb = wk & 31, h = (wk >> 5) & 7, split = wk >> 8;

    const int q0 = qb * 128 + wv * 32;
    const int kstart = split * nkeys;
    const int ntiles = nkeys >> 6;

    const bf16_t* Qh = Qb + h * 4096 * 128;
    const bf16_t* Kh = Kb + h * 4096 * 128;
    const bf16_t* Vh = Vt + h * 64 * 4096;

    bf16x8 qf[2][4];
    #pragma unroll
    for (int qt = 0; qt < 2; qt++)
        #pragma unroll
        for (int c = 0; c < 4; c++)
            qf[qt][c] = *(const bf16x8*)(Qh + (q0 + qt * 16 + qi) * 128 + c * 32 + g * 8);

    float m[2] = {-1e30f, -1e30f}, l[2] = {0.f, 0.f};
    f32x4 oacc[2][4];
    #pragma unroll
    for (int qt = 0; qt < 2; qt++)
        #pragma unroll
        for (int c = 0; c < 4; c++) oacc[qt][c] = (f32x4){0.f,0.f,0.f,0.f};

    stage_k(&k_lds[0][0], Kh, kstart, wv, lane);
    __syncthreads();

    for (int it = 0; it < ntiles; ++it) {
        const int cur = it & 1;
        const int kt = kstart + it * 64;
        if (it + 1 < ntiles) stage_k(&k_lds[cur ^ 1][0], Kh, kt + 64, wv, lane);

        // S^T = K Q^T : lane holds 16 scores (keys 16t+4g+i) for q = q0+qt*16+qi
        f32x4 s[2][4];
        #pragma unroll
        for (int qt = 0; qt < 2; qt++)
            #pragma unroll
            for (int t = 0; t < 4; t++) s[qt][t] = (f32x4){0.f,0.f,0.f,0.f};
        __builtin_amdgcn_s_setprio(1);
        #pragma unroll
        for (int t = 0; t < 4; t++) {
            const bf16_t* kr = &k_lds[cur][(t * 16 + qi) * 128];
            #pragma unroll
            for (int c = 0; c < 4; c++) {
                int offb = (c * 64 + g * 16) ^ ((qi & 7) << 4);
                bf16x8 kf = *(const bf16x8*)(kr + (offb >> 1));
                s[0][t] = mfma16(kf, qf[0][c], s[0][t]);
                s[1][t] = mfma16(kf, qf[1][c], s[1][t]);
            }
        }
        __builtin_amdgcn_s_setprio(0);

        // in-lane online softmax (log2 domain)
        float mx[2];
        #pragma unroll
        for (int qt = 0; qt < 2; qt++) {
            float a = fmaxf(vmax4(s[qt][0]), vmax4(s[qt][1]));
            float b = fmaxf(vmax4(s[qt][2]), vmax4(s[qt][3]));
            float v = fmaxf(a, b);
            v = fmaxf(v, __shfl_xor(v, 16));
            v = fmaxf(v, __shfl_xor(v, 32));
            mx[qt] = v;
        }
        float dmax = fmaxf(mx[0] - m[0], mx[1] - m[1]);
        if (__any(dmax > DEFER_THR)) {
            #pragma unroll
            for (int qt = 0; qt < 2; qt++) {
                float mn = fmaxf(m[qt], mx[qt]);
                float al = __builtin_amdgcn_exp2f(m[qt] - mn);
                l[qt] *= al;
                #pragma unroll
                for (int c = 0; c < 4; c++)
                    #pragma unroll
                    for (int i = 0; i < 4; i++) oacc[qt][c][i] *= al;
                m[qt] = mn;
            }
        }
        float p[2][4][4];
        #pragma unroll
        for (int qt = 0; qt < 2; qt++) {
            float ks = 0.f;
            #pragma unroll
            for (int t = 0; t < 4; t++)
                #pragma unroll
                for (int i = 0; i < 4; i++) {
                    float e = __builtin_amdgcn_exp2f(s[qt][t][i] - m[qt]);
                    p[qt][t][i] = e;
                    ks += e;
                }
            ks += __shfl_xor(ks, 16);
            ks += __shfl_xor(ks, 32);
            l[qt] += ks;
        }

        // pack P -> B-frags (pure in-lane)
        bf16x8 pb[2][2];
        #pragma unroll
        for (int qt = 0; qt < 2; qt++)
            #pragma unroll
            for (int u = 0; u < 2; u++) {
                bf16x8 t8;
                #pragma unroll
                for (int e = 0; e < 4; e++) {
                    t8[e]     = (bf16_t)p[qt][2 * u][e];
                    t8[4 + e] = (bf16_t)p[qt][2 * u + 1][e];
                }
                pb[qt][u] = t8;
            }

        // O^T += V^T P^T (Vt time-permuted so A-frag is one contiguous b128)
        __builtin_amdgcn_s_setprio(1);
        #pragma unroll
        for (int c = 0; c < 4; c++)
            #pragma unroll
            for (int u = 0; u < 2; u++) {
                bf16x8 vf = *(const bf16x8*)(Vh + (c * 16 + qi) * 4096 + kt + u * 32 + g * 8);
                oacc[0][c] = mfma16(vf, pb[0][u], oacc[0][c]);
                oacc[1][c] = mfma16(vf, pb[1][u], oacc[1][c]);
            }
        __builtin_amdgcn_s_setprio(0);

        __syncthreads();
    }

    if (gridDim.z == 1) {
        #pragma unroll
        for (int qt = 0; qt < 2; qt++) {
            float inv = 1.0f / l[qt];
            int q = q0 + qt * 16 + qi;
            #pragma unroll
            for (int c = 0; c < 4; c++) {
                bf16x4 o4;
                #pragma unroll
                for (int i = 0; i < 4; i++) o4[i] = (bf16_t)(oacc[qt][c][i] * inv);
                *(bf16x4*)(Cb + q * 512 + h * 64 + c * 16 + g * 4) = o4;
            }
        }
    } else {
        #pragma unroll
        for (int qt = 0; qt < 2; qt++) {
            int q = q0 + qt * 16 + qi;
            float* Op = Opart + ((size_t)(split * 8 + h) * 4096 + q) * 64;
            #pragma unroll
            for (int c = 0; c < 4; c++)
                *(f32x4*)(Op + c * 16 + g * 4) = oacc[qt][c];
            if (g == 0) {
                float* mlp = MLpart + ((size_t)(split * 8 + h) * 4096 + q) * 2;
                mlp[0] = m[qt];
                mlp[1] = l[qt];
            }
        }
    }
}

// combine `splits` key-splits (m in log2 domain); 4 dv per thread
__global__ void k_merge(const float* __restrict__ Opart, const float* __restrict__ MLpart,
                        bf16_t* __restrict__ Cb, int splits) {
    int idx = blockIdx.x * 256 + threadIdx.x;   // 4096*512/4
    int q = idx >> 7, rem = idx & 127;
    int hv4 = rem * 4;
    int h = hv4 >> 6, dv = hv4 & 63;

    float M = -1e30f;
    float ms[4], ls[4];
    for (int s = 0; s < splits; s++) {
        const float* mlp = MLpart + ((size_t)(s * 8 + h) * 4096 + q) * 2;
        ms[s] = mlp[0]; ls[s] = mlp[1];
        M = fmaxf(M, ms[s]);
    }
    f32x4 acc = {0.f, 0.f, 0.f, 0.f};
    float L = 0.f;
    for (int s = 0; s < splits; s++) {
        float w = __builtin_amdgcn_exp2f(ms[s] - M);
        f32x4 ov = *(const f32x4*)(Opart + ((size_t)(s * 8 + h) * 4096 + q) * 64 + dv);
        #pragma unroll
        for (int e = 0; e < 4; e++) acc[e] += ov[e] * w;
        L += ls[s] * w;
    }
    float inv = 1.0f / L;
    bf16x4 o4;
    #pragma unroll
    for (int e = 0; e < 4; e++) o4[e] = (bf16_t)(acc[e] * inv);
    *(bf16x4*)(Cb + (size_t)q * 512 + hv4) = o4;
}

// ---------------- output projection ----------------
__global__ __launch_bounds__(256) void k_gemm_out(
        const bf16_t* __restrict__ Cb, const bf16_t* __restrict__ Wot,
        const float* __restrict__ bo, float* __restrict__ out) {
    int lane = threadIdx.x & 63, wv = threadIdx.x >> 6;
    int rbase = blockIdx.x * 128 + wv * 32;
    int cbase = blockIdx.y * 64;
    int row = lane & 15, g = lane >> 4;

    const bf16_t* ap = Cb + (rbase + row) * 512 + g * 8;
    const bf16_t* bp = Wot + (cbase + row) * 512 + g * 8;
    f32x4 acc[2][4];
    #pragma unroll
    for (int at = 0; at < 2; at++)
        #pragma unroll
        for (int cc = 0; cc < 4; cc++) acc[at][cc] = (f32x4){0.f,0.f,0.f,0.f};
    #pragma unroll 4
    for (int kk = 0; kk < 512; kk += 32) {
        bf16x8 a0 = *(const bf16x8*)(ap + kk);
        bf16x8 a1 = *(const bf16x8*)(ap + 16 * 512 + kk);
        #pragma unroll
        for (int cc = 0; cc < 4; cc++) {
            bf16x8 b = *(const bf16x8*)(bp + cc * 16 * 512 + kk);
            acc[0][cc] = mfma16(a0, b, acc[0][cc]);
            acc[1][cc] = mfma16(a1, b, acc[1][cc]);
        }
    }

    #pragma unroll
    for (int cc = 0; cc < 4; cc++) {
        float bias = bo[cbase + cc * 16 + row];
        #pragma unroll
        for (int at = 0; at < 2; at++)
            #pragma unroll
            for (int i = 0; i < 4; i++)
                out[(rbase + at * 16 + g * 4 + i) * 512 + cbase + cc * 16 + row] =
                    acc[at][cc][i] + bias;
    }
}

// ---------------- launch ----------------
extern "C" void kernel_launch(void* const* d_in, const int* in_sizes, int n_in,
                              void* d_out, int out_size, void* d_ws, size_t ws_size,
                              hipStream_t stream) {
    const float* x  = (const float*)d_in[0];
    const float* Wq = (const float*)d_in[1];
    const float* bq = (const float*)d_in[2];
    const float* Wk = (const float*)d_in[3];
    const float* bk = (const float*)d_in[4];
    const float* Wv = (const float*)d_in[5];
    const float* bv = (const float*)d_in[6];
    const float* Wo = (const float*)d_in[7];
    const float* bo = (const float*)d_in[8];
    float* out = (float*)d_out;

    char* ws = (char*)d_ws;
    bf16_t* xb    = (bf16_t*)(ws + 0);          // 4,194,304
    bf16_t* Wcat  = (bf16_t*)(ws + 4194304);    // 2,621,440
    bf16_t* Qb    = (bf16_t*)(ws + 6815744);    // 8,388,608
    bf16_t* Kb    = (bf16_t*)(ws + 15204352);   // 8,388,608
    bf16_t* Vt    = (bf16_t*)(ws + 23592960);   // 4,194,304 (time-permuted)
    bf16_t* Cb    = (bf16_t*)(ws + 27787264);   // 4,194,304
    bf16_t* Wot   = (bf16_t*)(ws + 31981568);   // 524,288
    float*  bcat  = (float*)(ws + 32505856);    // 10,240
    float*  Opart = (float*)(ws + 32516096);    // up to 4*8*4096*64*4 = 33,554,432
    float*  MLprt = (float*)(ws + 66070528);    // up to 4*8*4096*2*4  = 1,048,576
    const size_t NEED4 = 67119104;
    // splits=2 layout fits inside the splits=4 region
    int splits = (ws_size >= NEED4) ? 4 : ((ws_size >= 50341888) ? 2 : 1);

    hipLaunchKernelGGL(k_stage_x,    dim3(2048),   dim3(256), 0, stream, x, xb);
    hipLaunchKernelGGL(k_stage_wt,   dim3(128, 3), dim3(256), 0, stream, Wq, Wk, Wv, Wcat);
    hipLaunchKernelGGL(k_stage_bias, dim3(10),     dim3(256), 0, stream, bq, bk, bv, bcat);
    hipLaunchKernelGGL(k_stage_wo_t, dim3(8, 8),   dim3(256), 0, stream, Wo, Wot);
    hipLaunchKernelGGL(k_gemm_qkv,   dim3(32, 40), dim3(256), 0, stream, xb, Wcat, bcat, Qb, Kb, Vt);
    hipLaunchKernelGGL(k_attn,       dim3(32, 8, splits), dim3(256), 0, stream, Qb, Kb, Vt, Cb, Opart, MLprt, 4096 / splits);
    if (splits > 1)
        hipLaunchKernelGGL(k_merge,  dim3(2048),   dim3(256), 0, stream, Opart, MLprt, Cb, splits);
    hipLaunchKernelGGL(k_gemm_out,   dim3(32, 8),  dim3(256), 0, stream, Cb, Wot, bo, out);
}